// Round 1
// 321.034 us; speedup vs baseline: 1.1188x; 1.1188x over previous
//
#include <hip/hip_runtime.h>
#include <math.h>

typedef float v4f __attribute__((ext_vector_type(4)));

#define XS 2048
#define NN 4096
#define ZS 64
#define DD 6208
#define D4 1552              // DD/4 chunks per row
#define Z0 (XS + NN)         // 6144
#define TOPK 16
#define ZTOPK 8
#define EPS_TIE 1e-9f
#define RNDC 0.5f
#define NXUPD 2047           // x rows updated: 0..2046

// d_out offsets (floats): [z_response(64) | final(6208) | neurons(DD*DD) | ages(6208)]
#define OUT_FINAL 64
#define OUT_NEUR  (64 + DD)
#define OUT_AGES  (OUT_NEUR + (size_t)DD * DD)

// ws offsets (floats)
#define WS_RESP   0
#define WS_INPT   DD
#define WS_MIXX   (2 * DD)
#define WS_MIXZ   (3 * DD)
#define WS_MIXY   (4 * DD)
#define WS_SCAL   (5 * DD)           // 0 Sii,1 SmmX,2 SmiX,3 SmmZ,4 SmiZ,5 SmmY,6 SmiY,7 denomX
#define WS_SELROW (WS_SCAL + 32)     // 24 ints
#define WS_SELC   (WS_SELROW + 24)   // 24 floats: v/a
#define WS_SELW   (WS_SELC + 24)     // 24 floats: (a-1)/a
#define WS_TOTAL  (WS_SELW + 32)

// x-part tiling: 256 row-groups (8 rows) x 4 column splits of 388 chunks
#define XBLKS 1024
#define CSPL  388
#define YZBLKS (DD - XS)             // 4160
#define AUXBLKS 11                   // ages-base (6208) + final-zero (4160) = 10368 elems / 1024

// mix_x partial reduce: 388 blocks x 4 chunks each, summing 256 partial rows
#define RBLKS 388

__device__ __forceinline__ v4f ld4(const float* p) { return *(const v4f*)p; }
__device__ __forceinline__ v4f v4z() { v4f v; v.x = v.y = v.z = v.w = 0.f; return v; }
__device__ __forceinline__ float dot4(v4f a, v4f b) {
  return fmaf(a.x, b.x, fmaf(a.y, b.y, fmaf(a.z, b.z, a.w * b.w)));
}
__device__ __forceinline__ v4f load_inpt(const float* x, const float* yr,
                                         const float* zv, int c) {
  int col = c * 4;   // chunk boundaries never straddle 2048 / 6144 (both %4==0)
  if (col < XS) return ld4(x + col);
  if (col < Z0) return ld4(yr + (col - XS));
  return ld4(zv + (col - Z0));
}
__device__ __forceinline__ v4f wred4(v4f a) {
  #pragma unroll
  for (int m = 32; m >= 1; m >>= 1) {
    a.x += __shfl_xor(a.x, m); a.y += __shfl_xor(a.y, m);
    a.z += __shfl_xor(a.z, m); a.w += __shfl_xor(a.w, m);
  }
  return a;
}

// ---------------- Phase 1: matvec + copy rows>=2047 + partial mix_x + aux ---
__global__ __launch_bounds__(256) void k_phase1(
    const float* __restrict__ x, const float* __restrict__ yr,
    const float* __restrict__ zv, const float* __restrict__ neurons,
    const float* __restrict__ ages, float* __restrict__ ws,
    float* __restrict__ out)
{
  const int t = threadIdx.x;
  const int b = blockIdx.x;
  float* outn = out + OUT_NEUR;

  if (b < XBLKS) {
    // ---- x-part: rows rg*8..rg*8+7, columns [cs*388, cs*388+388) chunks ----
    const int rg = b >> 2, cs = b & 3;
    const int row0 = rg * 8;
    const int cbase = cs * CSPL;
    const int c0 = cbase + t;            // always valid (t<256<=388)
    const int c1 = cbase + 256 + t;      // valid iff t<132
    const bool has1 = (t < CSPL - 256);

    v4f i0 = load_inpt(x, yr, zv, c0);
    v4f i1 = has1 ? load_inpt(x, yr, zv, c1) : v4z();
    if (b < 4) {  // rg==0 blocks stage inpt (each covers its column quarter)
      ((v4f*)(ws + WS_INPT))[c0] = i0;
      if (has1) ((v4f*)(ws + WS_INPT))[c1] = i1;
    }

    float wr[8];
    #pragma unroll
    for (int r = 0; r < 8; ++r) {
      float a = ages[row0 + r];
      wr[r] = (row0 + r < NXUPD) ? (a - 1.f) / a : 0.f;
    }

    float dot[8];
    v4f m0 = v4z(), m1 = v4z();
    #pragma unroll
    for (int r = 0; r < 8; ++r) {
      const int row = row0 + r;
      const float* rp = neurons + (size_t)row * DD;
      v4f a0 = ld4(rp + 4 * c0);
      v4f a1 = has1 ? ld4(rp + 4 * c1) : v4z();
      dot[r] = dot4(a0, i0) + dot4(a1, i1);
      m0 += wr[r] * a0;
      m1 += wr[r] * a1;
      if (row >= NXUPD) {   // only row 2047 here: copy to output
        __builtin_nontemporal_store(a0, (v4f*)(outn + (size_t)row * DD + 4 * c0));
        if (has1)
          __builtin_nontemporal_store(a1, (v4f*)(outn + (size_t)row * DD + 4 * c1));
      }
    }

    // block-reduce the 8 partial dots, atomic into resp (4 col-splits/row)
    __shared__ float wred[4][8];
    const int lane = t & 63, wv = t >> 6;
    #pragma unroll
    for (int r = 0; r < 8; ++r) {
      float v = dot[r];
      #pragma unroll
      for (int m = 32; m >= 1; m >>= 1) v += __shfl_xor(v, m);
      if (lane == 0) wred[wv][r] = v;
    }
    __syncthreads();
    if (t < 8)
      atomicAdd(ws + WS_RESP + row0 + t,
                wred[0][t] + wred[1][t] + wred[2][t] + wred[3][t]);

    // partial mix_x: plain stores into dead output row rg (rows 0..255 are
    // fully overwritten by phase4, rows 0..2046). No atomics, no memset.
    float* pm = outn + (size_t)rg * DD;
    *(v4f*)(pm + 4 * c0) = m0;
    if (has1) *(v4f*)(pm + 4 * c1) = m1;
  } else if (b < XBLKS + YZBLKS) {
    // ---- yz-part: one full row per block, rows 2048..6207 ----
    const int row = 2048 + (b - XBLKS);
    const float* rp = neurons + (size_t)row * DD;
    float* op = outn + (size_t)row * DD;
    float dot = 0.f;
    #pragma unroll
    for (int k = 0; k < 6; ++k) {        // chunks t+256k, max 1535 < 1552
      const int c = t + 256 * k;
      v4f a = ld4(rp + 4 * c);
      v4f iv = load_inpt(x, yr, zv, c);
      dot += dot4(a, iv);
      __builtin_nontemporal_store(a, (v4f*)(op + 4 * c));
    }
    if (t < 16) {                        // epilogue chunks 1536..1551 (z region)
      const int c = 1536 + t;
      v4f a = ld4(rp + 4 * c);
      v4f iv = ld4(zv + (4 * c - Z0));
      dot += dot4(a, iv);
      __builtin_nontemporal_store(a, (v4f*)(op + 4 * c));
    }
    __shared__ float red[4];
    const int lane = t & 63, wv = t >> 6;
    #pragma unroll
    for (int m = 32; m >= 1; m >>= 1) dot += __shfl_xor(dot, m);
    if (lane == 0) red[wv] = dot;
    __syncthreads();
    if (t == 0) ws[WS_RESP + row] = red[0] + red[1] + red[2] + red[3];
  } else {
    // ---- aux blocks: ages base (+1 for x rows) and final zero-fill [XS..DD) -
    const int e = b - (XBLKS + YZBLKS);
    const int base = e * 1024;
    #pragma unroll
    for (int k = 0; k < 4; ++k) {
      int j = base + t + 256 * k;
      if (j < DD) {
        out[OUT_AGES + j] = ages[j] + ((j < NXUPD) ? 1.f : 0.f);
      } else {
        int f = j - DD;
        if (f < DD - XS) out[OUT_FINAL + XS + f] = 0.f;
      }
    }
  }
}

// ---------------- Phase 2: top-ks, final, z_response, sel tables -----------
__global__ __launch_bounds__(1024) void k_phase2(
    const float* __restrict__ ages, float* __restrict__ ws, float* __restrict__ out)
{
  const int t = threadIdx.x;
  const int lane = t & 63, wv = t >> 6;
  __shared__ float s_candv[16 * (TOPK + 1)];
  __shared__ int   s_candi[16 * (TOPK + 1)];
  __shared__ float s_zval[ZTOPK + 1];
  __shared__ int   s_zidx[ZTOPK + 1];
  __shared__ float s_yval[TOPK + 1];
  __shared__ int   s_yidx[TOPK + 1];
  __shared__ float s_red[16];
  __shared__ int   s_redi[16];
  __shared__ float s_denx, s_ty;

  float* resp = ws + WS_RESP;
  float* fin  = out + OUT_FINAL;
  float* oag  = out + OUT_AGES;

  // ---- A1: x max & nonzero flag, per-wave partials (no barriers) ----
  {
    float v0 = resp[t], v1 = resp[t + 1024];
    float lm = fmaxf(v0, v1);
    int nz = (v0 != 0.f) | (v1 != 0.f);
    #pragma unroll
    for (int m = 1; m < 64; m <<= 1) { lm = fmaxf(lm, __shfl_xor(lm, m)); nz |= __shfl_xor(nz, m); }
    if (lane == 0) { s_red[wv] = lm; s_redi[wv] = nz; }
  }

  // ---- A2: y wave-local top-17 in registers (lex-max (v,-i)), no barriers --
  {
    float v[4]; int id[4];
    #pragma unroll
    for (int q = 0; q < 4; ++q) { int i = (wv << 8) + (q << 6) + lane; id[q] = i; v[q] = resp[XS + i]; }
    for (int j = 0; j <= TOPK; ++j) {
      float bv = v[0]; int bi = id[0];
      #pragma unroll
      for (int q = 1; q < 4; ++q)
        if (v[q] > bv || (v[q] == bv && id[q] < bi)) { bv = v[q]; bi = id[q]; }
      #pragma unroll
      for (int m = 1; m < 64; m <<= 1) {
        float ov = __shfl_xor(bv, m); int oi = __shfl_xor(bi, m);
        if (ov > bv || (ov == bv && oi < bi)) { bv = ov; bi = oi; }
      }
      if (lane == 0) { s_candv[wv * (TOPK + 1) + j] = bv; s_candi[wv * (TOPK + 1) + j] = bi; }
      #pragma unroll
      for (int q = 0; q < 4; ++q) if (id[q] == bi) v[q] = -INFINITY;
    }
  }

  // ---- A3: z top-9 (wave 0, registers) ----
  if (wv == 0) {
    float v = resp[Z0 + lane];
    for (int j = 0; j <= ZTOPK; ++j) {
      float bv = v; int bi = lane;
      #pragma unroll
      for (int m = 1; m < 64; m <<= 1) {
        float ov = __shfl_xor(bv, m); int oi = __shfl_xor(bi, m);
        if (ov > bv || (ov == bv && oi < bi)) { bv = ov; bi = oi; }
      }
      if (lane == 0) { s_zval[j] = bv; s_zidx[j] = bi; }
      if (lane == bi) v = -INFINITY;
    }
  }

  __syncthreads();

  // ---- B: denx (wave1 lane0) || y merge of 272 candidates (wave0) ----
  if (t == 64) {
    float m2 = -INFINITY; int n2 = 0;
    for (int q = 0; q < 16; ++q) { m2 = fmaxf(m2, s_red[q]); n2 |= s_redi[q]; }
    float dx = m2 + EPS_TIE * (n2 ? 0.f : 1.f) * RNDC;
    s_denx = dx;
    ws[WS_SCAL + 7] = dx;
  }
  if (wv == 0) {
    float mv[5]; int mi[5];
    #pragma unroll
    for (int q = 0; q < 5; ++q) {
      int k = lane + (q << 6);
      if (k < 16 * (TOPK + 1)) { mv[q] = s_candv[k]; mi[q] = s_candi[k]; }
      else { mv[q] = -INFINITY; mi[q] = 0x7fffffff; }
    }
    for (int j = 0; j <= TOPK; ++j) {
      float bv = mv[0]; int bi = mi[0];
      #pragma unroll
      for (int q = 1; q < 5; ++q)
        if (mv[q] > bv || (mv[q] == bv && mi[q] < bi)) { bv = mv[q]; bi = mi[q]; }
      #pragma unroll
      for (int m = 1; m < 64; m <<= 1) {
        float ov = __shfl_xor(bv, m); int oi = __shfl_xor(bi, m);
        if (ov > bv || (ov == bv && oi < bi)) { bv = ov; bi = oi; }
      }
      if (lane == 0) { s_yval[j] = bv; s_yidx[j] = bi; }
      #pragma unroll
      for (int q = 0; q < 5; ++q) if (mi[q] == bi) mv[q] = -INFINITY;
    }
    if (lane == 0) {
      float ty = 0.f;
      for (int q = 0; q < TOPK; ++q) if (s_yval[q] == s_yval[TOPK]) ty = 1.f;
      s_ty = ty;
    }
  }
  __syncthreads();

  // ---- C: final x, scatters, z_response, sel tables, sel ages ----
  const float denx  = s_denx;
  fin[t]        = resp[t] / denx;
  fin[t + 1024] = resp[t + 1024] / denx;

  const float zlast = s_zval[ZTOPK];
  const float zden  = s_zval[0] - zlast;
  const float ylast = s_yval[TOPK];
  const float yden  = s_yval[0] - ylast + EPS_TIE * s_ty * RNDC;

  if (t < ZTOPK) {
    int zi = s_zidx[t];
    int row = Z0 + zi;
    fin[row] = (s_zval[t] - zlast) / zden;
    float a = ages[row];
    ((int*)(ws + WS_SELROW))[t] = row;
    ws[WS_SELC + t] = s_zval[t] / a;
    ws[WS_SELW + t] = (a - 1.f) / a;
    oag[row] = a + 1.f;
  } else if (t >= 32 && t < 32 + TOPK) {
    int k = t - 32;
    int row = XS + s_yidx[k];
    fin[row] = (s_yval[k] - ylast) / yden;
    float a = ages[row];
    ((int*)(ws + WS_SELROW))[ZTOPK + k] = row;
    ws[WS_SELC + ZTOPK + k] = s_yval[k] / a;
    ws[WS_SELW + ZTOPK + k] = (a - 1.f) / a;
    oag[row] = a + 1.f;
  } else if (t >= 128 && t < 192) {
    int i = t - 128;
    float v = 0.f;
    for (int k = 0; k < ZTOPK; ++k) if (s_zidx[k] == i) v = (s_zval[k] - zlast) / zden;
    out[i] = v;
  }
}

// ---------------- Phase 3a: mix_z/mix_y accum + mix_x partial reduce -------
__global__ __launch_bounds__(256) void k_phase3a(
    const float* __restrict__ neurons, const float* __restrict__ outn,
    float* __restrict__ ws)
{
  const int b = blockIdx.x;
  const int t = threadIdx.x;
  if (b < ZTOPK + TOPK) {
    const int row = ((const int*)(ws + WS_SELROW))[b];
    const float w = ws[WS_SELW + b];
    float* dst = ws + ((b < ZTOPK) ? WS_MIXZ : WS_MIXY);
    const float* src = neurons + (size_t)row * DD;
    #pragma unroll
    for (int k = 0; k < 6; ++k) {
      const int c = t + 256 * k;
      v4f a = ld4(src + 4 * c);
      atomicAdd(dst + 4 * c + 0, w * a.x);
      atomicAdd(dst + 4 * c + 1, w * a.y);
      atomicAdd(dst + 4 * c + 2, w * a.z);
      atomicAdd(dst + 4 * c + 3, w * a.w);
    }
    if (t < 16) {
      const int c = 1536 + t;
      v4f a = ld4(src + 4 * c);
      atomicAdd(dst + 4 * c + 0, w * a.x);
      atomicAdd(dst + 4 * c + 1, w * a.y);
      atomicAdd(dst + 4 * c + 2, w * a.z);
      atomicAdd(dst + 4 * c + 3, w * a.w);
    }
  } else {
    // mix_x tree-reduce: sum 256 partial rows (outn rows 0..255) for 4 chunks
    const int g = b - (ZTOPK + TOPK);    // 0..387
    const int cb = 4 * g;                // chunk base
    const float* pr = outn + (size_t)t * DD + 4 * cb;
    v4f a0 = ld4(pr), a1 = ld4(pr + 4), a2 = ld4(pr + 8), a3 = ld4(pr + 12);
    a0 = wred4(a0); a1 = wred4(a1); a2 = wred4(a2); a3 = wred4(a3);
    __shared__ v4f sred[4][4];
    if ((t & 63) == 0) {
      int w = t >> 6;
      sred[w][0] = a0; sred[w][1] = a1; sred[w][2] = a2; sred[w][3] = a3;
    }
    __syncthreads();
    if (t < 4) {
      v4f s = sred[0][t] + sred[1][t] + sred[2][t] + sred[3][t];
      *(v4f*)(ws + WS_MIXX + 4 * (cb + t)) = s;
    }
  }
}

// ---------------- Phase 3b: all scalar dots --------------------------------
__global__ __launch_bounds__(1024) void k_phase3b(float* __restrict__ ws)
{
  const int t = threadIdx.x;
  __shared__ float red[16][7];
  const float* inpt = ws + WS_INPT;
  float s0 = 0.f, s1 = 0.f, s2 = 0.f, s3 = 0.f, s4 = 0.f, s5 = 0.f, s6 = 0.f;
  for (int i = t; i < DD; i += 1024) {
    float ip = inpt[i];
    float mx = ws[WS_MIXX + i], mz = ws[WS_MIXZ + i], my = ws[WS_MIXY + i];
    s0 = fmaf(ip, ip, s0);
    s1 = fmaf(mx, mx, s1); s2 = fmaf(mx, ip, s2);
    s3 = fmaf(mz, mz, s3); s4 = fmaf(mz, ip, s4);
    s5 = fmaf(my, my, s5); s6 = fmaf(my, ip, s6);
  }
  #pragma unroll
  for (int m = 1; m < 64; m <<= 1) {
    s0 += __shfl_xor(s0, m); s1 += __shfl_xor(s1, m); s2 += __shfl_xor(s2, m);
    s3 += __shfl_xor(s3, m); s4 += __shfl_xor(s4, m); s5 += __shfl_xor(s5, m);
    s6 += __shfl_xor(s6, m);
  }
  if ((t & 63) == 0) {
    int w = t >> 6;
    red[w][0] = s0; red[w][1] = s1; red[w][2] = s2; red[w][3] = s3;
    red[w][4] = s4; red[w][5] = s5; red[w][6] = s6;
  }
  __syncthreads();
  if (t == 0) {
    float a[7] = {0.f, 0.f, 0.f, 0.f, 0.f, 0.f, 0.f};
    for (int q = 0; q < 16; ++q)
      for (int k = 0; k < 7; ++k) a[k] += red[q][k];
    float* scal = ws + WS_SCAL;
    for (int k = 0; k < 7; ++k) scal[k] = a[k];
  }
}

// ---------------- Phase 4: write the 2071 updated rows ---------------------
__global__ __launch_bounds__(256) void k_phase4(
    const float* __restrict__ ages, const float* __restrict__ ws,
    float* __restrict__ outn)
{
  const int b = blockIdx.x;
  const int t = threadIdx.x;
  const float sii = ws[WS_SCAL + 0];
  int row; float c, smm, smi; const float* mix;
  if (b < NXUPD) {
    row = b;
    float a = ages[row];
    c = (ws[WS_RESP + row] / ws[WS_SCAL + 7]) / a;   // xvals[row] / age
    mix = ws + WS_MIXX; smm = ws[WS_SCAL + 1]; smi = ws[WS_SCAL + 2];
  } else {
    int k = b - NXUPD;
    row = ((const int*)(ws + WS_SELROW))[k];
    c = ws[WS_SELC + k];
    if (k < ZTOPK) { mix = ws + WS_MIXZ; smm = ws[WS_SCAL + 3]; smi = ws[WS_SCAL + 4]; }
    else           { mix = ws + WS_MIXY; smm = ws[WS_SCAL + 5]; smi = ws[WS_SCAL + 6]; }
  }
  // ||mix + c*inpt||^2 = smm + 2c*smi + c^2*sii
  const float inv = 1.f / (sqrtf(fmaf(c, fmaf(c, sii, 2.f * smi), smm)) + 1e-12f);
  const float* inpt = ws + WS_INPT;
  float* dst = outn + (size_t)row * DD;
  #pragma unroll
  for (int k = 0; k < 6; ++k) {
    const int i = t + 256 * k;
    v4f m4 = ((const v4f*)(mix))[i];
    v4f i4 = ((const v4f*)(inpt))[i];
    v4f o = (m4 + c * i4) * inv;
    __builtin_nontemporal_store(o, (v4f*)dst + i);
  }
  if (t < 16) {
    const int i = 1536 + t;
    v4f m4 = ((const v4f*)(mix))[i];
    v4f i4 = ((const v4f*)(inpt))[i];
    v4f o = (m4 + c * i4) * inv;
    __builtin_nontemporal_store(o, (v4f*)dst + i);
  }
}

// ---------------- launcher -------------------------------------------------
extern "C" void kernel_launch(void* const* d_in, const int* in_sizes, int n_in,
                              void* d_out, int out_size, void* d_ws, size_t ws_size,
                              hipStream_t stream)
{
  (void)in_sizes; (void)n_in; (void)out_size; (void)ws_size;
  const float* x    = (const float*)d_in[0];
  const float* zin  = (const float*)d_in[1];   // setup order: x, z, y_response, neurons, ages
  const float* yr   = (const float*)d_in[2];
  const float* neur = (const float*)d_in[3];
  const float* ages = (const float*)d_in[4];
  float* out = (float*)d_out;
  float* ws  = (float*)d_ws;

  hipMemsetAsync(d_ws, 0, (size_t)WS_TOTAL * sizeof(float), stream);
  k_phase1<<<XBLKS + YZBLKS + AUXBLKS, 256, 0, stream>>>(x, yr, zin, neur, ages, ws, out);
  k_phase2<<<1, 1024, 0, stream>>>(ages, ws, out);
  k_phase3a<<<ZTOPK + TOPK + RBLKS, 256, 0, stream>>>(neur, out + OUT_NEUR, ws);
  k_phase3b<<<1, 1024, 0, stream>>>(ws);
  k_phase4<<<NXUPD + ZTOPK + TOPK, 256, 0, stream>>>(ages, ws, out + OUT_NEUR);
}

// Round 2
// 317.643 us; speedup vs baseline: 1.1307x; 1.0107x over previous
//
#include <hip/hip_runtime.h>
#include <math.h>

typedef float v4f __attribute__((ext_vector_type(4)));

#define XS 2048
#define NN 4096
#define ZS 64
#define DD 6208
#define D4 1552              // DD/4 chunks per row
#define Z0 (XS + NN)         // 6144
#define TOPK 16
#define ZTOPK 8
#define EPS_TIE 1e-9f
#define RNDC 0.5f
#define NXUPD 2047           // x rows updated: 0..2046

// d_out offsets (floats): [z_response(64) | final(6208) | neurons(DD*DD) | ages(6208)]
#define OUT_FINAL 64
#define OUT_NEUR  (64 + DD)
#define OUT_AGES  (OUT_NEUR + (size_t)DD * DD)

// ws offsets (floats) — no region requires pre-zeroing
#define WS_RESP    0                         // rows >= 2048 written directly
#define WS_RESPP   DD                        // 4 x 2048 x-row dot partials
#define WS_INPT    (DD + 8192)
#define WS_MIXX    (WS_INPT + DD)
#define WS_MIXZ    (WS_MIXX + DD)
#define WS_MIXY    (WS_MIXZ + DD)
#define WS_SCAL    (WS_MIXY + DD)            // [7] = denomX (written by phase2)
#define WS_SCALPAD (WS_SCAL + 32)            // 7 scalars x 64 slots (zeroed by phase2)
#define WS_SELROW  (WS_SCALPAD + 448)        // 24 ints
#define WS_SELC    (WS_SELROW + 24)          // 24 floats: v/a
#define WS_SELW    (WS_SELC + 24)            // 24 floats: (a-1)/a
#define WS_TOTAL   (WS_SELW + 32)

// scalpad scalar ids: 0 Sii, 1 SmmX, 2 SmiX, 3 SmmZ, 4 SmiZ, 5 SmmY, 6 SmiY

// x-part tiling: 256 row-groups (8 rows) x 4 column splits of 388 chunks
#define XBLKS 1024
#define CSPL  388
#define YZBLKS (DD - XS)             // 4160
#define AUXBLKS 11                   // ages-base (6208) + final-zero (4160) = 10368 / 1024

// mix_x partial reduce: 388 blocks x 4 chunks; gather: 16 blocks x 97 chunks
#define RBLKS 388
#define GBLKS 16

__device__ __forceinline__ v4f ld4(const float* p) { return *(const v4f*)p; }
__device__ __forceinline__ v4f v4z() { v4f v; v.x = v.y = v.z = v.w = 0.f; return v; }
__device__ __forceinline__ float dot4(v4f a, v4f b) {
  return fmaf(a.x, b.x, fmaf(a.y, b.y, fmaf(a.z, b.z, a.w * b.w)));
}
__device__ __forceinline__ v4f load_inpt(const float* x, const float* yr,
                                         const float* zv, int c) {
  int col = c * 4;   // chunk boundaries never straddle 2048 / 6144 (both %4==0)
  if (col < XS) return ld4(x + col);
  if (col < Z0) return ld4(yr + (col - XS));
  return ld4(zv + (col - Z0));
}
__device__ __forceinline__ v4f wred4(v4f a) {
  #pragma unroll
  for (int m = 32; m >= 1; m >>= 1) {
    a.x += __shfl_xor(a.x, m); a.y += __shfl_xor(a.y, m);
    a.z += __shfl_xor(a.z, m); a.w += __shfl_xor(a.w, m);
  }
  return a;
}

// ---------------- Phase 1: matvec + copy rows>=2047 + partial mix_x + aux ---
__global__ __launch_bounds__(256, 4) void k_phase1(
    const float* __restrict__ x, const float* __restrict__ yr,
    const float* __restrict__ zv, const float* __restrict__ neurons,
    const float* __restrict__ ages, float* __restrict__ ws,
    float* __restrict__ out)
{
  const int t = threadIdx.x;
  const int b = blockIdx.x;
  float* outn = out + OUT_NEUR;

  if (b < XBLKS) {
    // ---- x-part: rows rg*8..rg*8+7, columns [cs*388, cs*388+388) chunks ----
    const int rg = b >> 2, cs = b & 3;
    const int row0 = rg * 8;
    const int cbase = cs * CSPL;
    const int c0 = cbase + t;            // always valid (t<256<=388)
    const int c1 = cbase + 256 + t;      // valid iff t<132
    const bool has1 = (t < CSPL - 256);

    v4f i0 = load_inpt(x, yr, zv, c0);
    v4f i1 = has1 ? load_inpt(x, yr, zv, c1) : v4z();
    if (b < 4) {  // rg==0 blocks stage inpt (each covers its column quarter)
      ((v4f*)(ws + WS_INPT))[c0] = i0;
      if (has1) ((v4f*)(ws + WS_INPT))[c1] = i1;
    }

    float wr[8];
    #pragma unroll
    for (int r = 0; r < 8; ++r) {
      float a = ages[row0 + r];
      wr[r] = (row0 + r < NXUPD) ? (a - 1.f) / a : 0.f;
    }

    // issue all row loads first (max memory-level parallelism)
    v4f a0[8], a1[8];
    #pragma unroll
    for (int r = 0; r < 8; ++r)
      a0[r] = ld4(neurons + (size_t)(row0 + r) * DD + 4 * c0);
    #pragma unroll
    for (int r = 0; r < 8; ++r)
      a1[r] = has1 ? ld4(neurons + (size_t)(row0 + r) * DD + 4 * c1) : v4z();

    float dot[8];
    v4f m0 = v4z(), m1 = v4z();
    #pragma unroll
    for (int r = 0; r < 8; ++r) {
      dot[r] = dot4(a0[r], i0) + dot4(a1[r], i1);
      m0 += wr[r] * a0[r];
      m1 += wr[r] * a1[r];
    }
    if (row0 + 7 >= NXUPD) {   // rg==255: row 2047 is not updated — copy it
      __builtin_nontemporal_store(a0[7], (v4f*)(outn + (size_t)2047 * DD + 4 * c0));
      if (has1)
        __builtin_nontemporal_store(a1[7], (v4f*)(outn + (size_t)2047 * DD + 4 * c1));
    }

    // block-reduce the 8 partial dots, plain store to partial array (no atomics)
    __shared__ float wred[4][8];
    const int lane = t & 63, wv = t >> 6;
    #pragma unroll
    for (int r = 0; r < 8; ++r) {
      float v = dot[r];
      #pragma unroll
      for (int m = 32; m >= 1; m >>= 1) v += __shfl_xor(v, m);
      if (lane == 0) wred[wv][r] = v;
    }
    __syncthreads();
    if (t < 8)
      ws[WS_RESPP + cs * 2048 + row0 + t] =
          wred[0][t] + wred[1][t] + wred[2][t] + wred[3][t];

    // partial mix_x: plain stores into dead output row rg (rows 0..255 are
    // fully overwritten by phase4). No atomics, no memset.
    float* pm = outn + (size_t)rg * DD;
    *(v4f*)(pm + 4 * c0) = m0;
    if (has1) *(v4f*)(pm + 4 * c1) = m1;
  } else if (b < XBLKS + YZBLKS) {
    // ---- yz-part: one full row per block, rows 2048..6207 ----
    const int row = 2048 + (b - XBLKS);
    const float* rp = neurons + (size_t)row * DD;
    float* op = outn + (size_t)row * DD;

    v4f a[6], iv[6];
    #pragma unroll
    for (int k = 0; k < 6; ++k) a[k] = ld4(rp + 4 * (t + 256 * k));
    #pragma unroll
    for (int k = 0; k < 6; ++k) iv[k] = load_inpt(x, yr, zv, t + 256 * k);

    float dot = 0.f;
    #pragma unroll
    for (int k = 0; k < 6; ++k) {
      dot += dot4(a[k], iv[k]);
      __builtin_nontemporal_store(a[k], (v4f*)op + (t + 256 * k));
    }
    if (t < 16) {                        // epilogue chunks 1536..1551 (z region)
      const int c = 1536 + t;
      v4f ae = ld4(rp + 4 * c);
      v4f ie = ld4(zv + (4 * c - Z0));
      dot += dot4(ae, ie);
      __builtin_nontemporal_store(ae, (v4f*)op + c);
    }
    __shared__ float red[4];
    const int lane = t & 63, wv = t >> 6;
    #pragma unroll
    for (int m = 32; m >= 1; m >>= 1) dot += __shfl_xor(dot, m);
    if (lane == 0) red[wv] = dot;
    __syncthreads();
    if (t == 0) ws[WS_RESP + row] = red[0] + red[1] + red[2] + red[3];
  } else {
    // ---- aux blocks: ages base (+1 for x rows) and final zero-fill [XS..DD) -
    const int e = b - (XBLKS + YZBLKS);
    const int base = e * 1024;
    #pragma unroll
    for (int k = 0; k < 4; ++k) {
      int j = base + t + 256 * k;
      if (j < DD) {
        out[OUT_AGES + j] = ages[j] + ((j < NXUPD) ? 1.f : 0.f);
      } else {
        int f = j - DD;
        if (f < DD - XS) out[OUT_FINAL + XS + f] = 0.f;
      }
    }
  }
}

// ---------------- Phase 2: top-ks, final, z_response, sel tables -----------
__global__ __launch_bounds__(1024) void k_phase2(
    const float* __restrict__ ages, float* __restrict__ ws, float* __restrict__ out)
{
  const int t = threadIdx.x;
  const int lane = t & 63, wv = t >> 6;
  __shared__ float s_xsum[XS];
  __shared__ float s_candv[16 * (TOPK + 1)];
  __shared__ int   s_candi[16 * (TOPK + 1)];
  __shared__ float s_zval[ZTOPK + 1];
  __shared__ int   s_zidx[ZTOPK + 1];
  __shared__ float s_yval[TOPK + 1];
  __shared__ int   s_yidx[TOPK + 1];
  __shared__ float s_red[16];
  __shared__ int   s_redi[16];
  __shared__ float s_denx, s_ty;

  float* resp = ws + WS_RESP;
  float* fin  = out + OUT_FINAL;
  float* oag  = out + OUT_AGES;

  // zero the scalar pad for phase3's atomics (no device memset needed)
  if (t < 448) ws[WS_SCALPAD + t] = 0.f;

  // ---- A1: x sums from 4 partials, max & nonzero flag ----
  {
    float v0 = 0.f, v1 = 0.f;
    #pragma unroll
    for (int cs = 0; cs < 4; ++cs) {
      v0 += ws[WS_RESPP + cs * 2048 + t];
      v1 += ws[WS_RESPP + cs * 2048 + t + 1024];
    }
    s_xsum[t] = v0; s_xsum[t + 1024] = v1;
    float lm = fmaxf(v0, v1);
    int nz = (v0 != 0.f) | (v1 != 0.f);
    #pragma unroll
    for (int m = 1; m < 64; m <<= 1) { lm = fmaxf(lm, __shfl_xor(lm, m)); nz |= __shfl_xor(nz, m); }
    if (lane == 0) { s_red[wv] = lm; s_redi[wv] = nz; }
  }

  // ---- A2: y wave-local top-17 in registers (lex-max (v,-i)), no barriers --
  {
    float v[4]; int id[4];
    #pragma unroll
    for (int q = 0; q < 4; ++q) { int i = (wv << 8) + (q << 6) + lane; id[q] = i; v[q] = resp[XS + i]; }
    for (int j = 0; j <= TOPK; ++j) {
      float bv = v[0]; int bi = id[0];
      #pragma unroll
      for (int q = 1; q < 4; ++q)
        if (v[q] > bv || (v[q] == bv && id[q] < bi)) { bv = v[q]; bi = id[q]; }
      #pragma unroll
      for (int m = 1; m < 64; m <<= 1) {
        float ov = __shfl_xor(bv, m); int oi = __shfl_xor(bi, m);
        if (ov > bv || (ov == bv && oi < bi)) { bv = ov; bi = oi; }
      }
      if (lane == 0) { s_candv[wv * (TOPK + 1) + j] = bv; s_candi[wv * (TOPK + 1) + j] = bi; }
      #pragma unroll
      for (int q = 0; q < 4; ++q) if (id[q] == bi) v[q] = -INFINITY;
    }
  }

  // ---- A3: z top-9 (wave 0, registers) ----
  if (wv == 0) {
    float v = resp[Z0 + lane];
    for (int j = 0; j <= ZTOPK; ++j) {
      float bv = v; int bi = lane;
      #pragma unroll
      for (int m = 1; m < 64; m <<= 1) {
        float ov = __shfl_xor(bv, m); int oi = __shfl_xor(bi, m);
        if (ov > bv || (ov == bv && oi < bi)) { bv = ov; bi = oi; }
      }
      if (lane == 0) { s_zval[j] = bv; s_zidx[j] = bi; }
      if (lane == bi) v = -INFINITY;
    }
  }

  __syncthreads();

  // ---- B: denx (wave1 lane0) || y merge of 272 candidates (wave0) ----
  if (t == 64) {
    float m2 = -INFINITY; int n2 = 0;
    for (int q = 0; q < 16; ++q) { m2 = fmaxf(m2, s_red[q]); n2 |= s_redi[q]; }
    float dx = m2 + EPS_TIE * (n2 ? 0.f : 1.f) * RNDC;
    s_denx = dx;
    ws[WS_SCAL + 7] = dx;
  }
  if (wv == 0) {
    float mv[5]; int mi[5];
    #pragma unroll
    for (int q = 0; q < 5; ++q) {
      int k = lane + (q << 6);
      if (k < 16 * (TOPK + 1)) { mv[q] = s_candv[k]; mi[q] = s_candi[k]; }
      else { mv[q] = -INFINITY; mi[q] = 0x7fffffff; }
    }
    for (int j = 0; j <= TOPK; ++j) {
      float bv = mv[0]; int bi = mi[0];
      #pragma unroll
      for (int q = 1; q < 5; ++q)
        if (mv[q] > bv || (mv[q] == bv && mi[q] < bi)) { bv = mv[q]; bi = mi[q]; }
      #pragma unroll
      for (int m = 1; m < 64; m <<= 1) {
        float ov = __shfl_xor(bv, m); int oi = __shfl_xor(bi, m);
        if (ov > bv || (ov == bv && oi < bi)) { bv = ov; bi = oi; }
      }
      if (lane == 0) { s_yval[j] = bv; s_yidx[j] = bi; }
      #pragma unroll
      for (int q = 0; q < 5; ++q) if (mi[q] == bi) mv[q] = -INFINITY;
    }
    if (lane == 0) {
      float ty = 0.f;
      for (int q = 0; q < TOPK; ++q) if (s_yval[q] == s_yval[TOPK]) ty = 1.f;
      s_ty = ty;
    }
  }
  __syncthreads();

  // ---- C: final x, scatters, z_response, sel tables, sel ages ----
  const float denx  = s_denx;
  fin[t]        = s_xsum[t] / denx;
  fin[t + 1024] = s_xsum[t + 1024] / denx;

  const float zlast = s_zval[ZTOPK];
  const float zden  = s_zval[0] - zlast;
  const float ylast = s_yval[TOPK];
  const float yden  = s_yval[0] - ylast + EPS_TIE * s_ty * RNDC;

  if (t < ZTOPK) {
    int zi = s_zidx[t];
    int row = Z0 + zi;
    fin[row] = (s_zval[t] - zlast) / zden;
    float a = ages[row];
    ((int*)(ws + WS_SELROW))[t] = row;
    ws[WS_SELC + t] = s_zval[t] / a;
    ws[WS_SELW + t] = (a - 1.f) / a;
    oag[row] = a + 1.f;
  } else if (t >= 32 && t < 32 + TOPK) {
    int k = t - 32;
    int row = XS + s_yidx[k];
    fin[row] = (s_yval[k] - ylast) / yden;
    float a = ages[row];
    ((int*)(ws + WS_SELROW))[ZTOPK + k] = row;
    ws[WS_SELC + ZTOPK + k] = s_yval[k] / a;
    ws[WS_SELW + ZTOPK + k] = (a - 1.f) / a;
    oag[row] = a + 1.f;
  } else if (t >= 128 && t < 192) {
    int i = t - 128;
    float v = 0.f;
    for (int k = 0; k < ZTOPK; ++k) if (s_zidx[k] == i) v = (s_zval[k] - zlast) / zden;
    out[i] = v;
  }
}

// ---------------- Phase 3: mix_x reduce + z/y gather + ALL scalars ---------
__global__ __launch_bounds__(256, 4) void k_phase3(
    const float* __restrict__ neurons, const float* __restrict__ outn,
    float* __restrict__ ws)
{
  const int b = blockIdx.x;
  const int t = threadIdx.x;

  if (b < RBLKS) {
    // mix_x tree-reduce: sum 256 partial rows (outn rows 0..255) for 4 chunks
    const int cb = 4 * b;                // chunk base
    const float* pr = outn + (size_t)t * DD + 4 * cb;
    v4f a0 = ld4(pr), a1 = ld4(pr + 4), a2 = ld4(pr + 8), a3 = ld4(pr + 12);
    a0 = wred4(a0); a1 = wred4(a1); a2 = wred4(a2); a3 = wred4(a3);
    __shared__ v4f sred[4][4];
    __shared__ float sp[4][3];
    if ((t & 63) == 0) {
      int w = t >> 6;
      sred[w][0] = a0; sred[w][1] = a1; sred[w][2] = a2; sred[w][3] = a3;
    }
    __syncthreads();
    if (t < 4) {
      v4f s = sred[0][t] + sred[1][t] + sred[2][t] + sred[3][t];
      *(v4f*)(ws + WS_MIXX + 4 * (cb + t)) = s;
      v4f ip = ld4(ws + WS_INPT + 4 * (cb + t));
      sp[t][0] = dot4(ip, ip);         // Sii partial
      sp[t][1] = dot4(s, s);           // SmmX partial
      sp[t][2] = dot4(s, ip);          // SmiX partial
    }
    __syncthreads();
    if (t == 0) {
      const int slot = b & 63;
      #pragma unroll
      for (int k = 0; k < 3; ++k) {
        float p = sp[0][k] + sp[1][k] + sp[2][k] + sp[3][k];
        atomicAdd(ws + WS_SCALPAD + k * 64 + slot, p);
      }
    }
  } else {
    // gather mix_z (8 sel rows) and mix_y (16 sel rows) for 97 chunks
    const int g = b - RBLKS;             // 0..15
    const int c = 97 * g + t;            // valid iff t<97
    const int* selr = (const int*)(ws + WS_SELROW);
    float p0 = 0.f, p1 = 0.f, p2 = 0.f, p3 = 0.f;
    if (t < 97) {
      v4f mz = v4z(), my = v4z();
      #pragma unroll
      for (int k = 0; k < ZTOPK; ++k) {
        const int row = selr[k];
        const float w = ws[WS_SELW + k];
        mz += w * ld4(neurons + (size_t)row * DD + 4 * c);
      }
      #pragma unroll
      for (int k = ZTOPK; k < ZTOPK + TOPK; ++k) {
        const int row = selr[k];
        const float w = ws[WS_SELW + k];
        my += w * ld4(neurons + (size_t)row * DD + 4 * c);
      }
      *(v4f*)(ws + WS_MIXZ + 4 * c) = mz;
      *(v4f*)(ws + WS_MIXY + 4 * c) = my;
      v4f ip = ld4(ws + WS_INPT + 4 * c);
      p0 = dot4(mz, mz); p1 = dot4(mz, ip);
      p2 = dot4(my, my); p3 = dot4(my, ip);
    }
    #pragma unroll
    for (int m = 1; m < 64; m <<= 1) {
      p0 += __shfl_xor(p0, m); p1 += __shfl_xor(p1, m);
      p2 += __shfl_xor(p2, m); p3 += __shfl_xor(p3, m);
    }
    __shared__ float gr[4][4];
    if ((t & 63) == 0) {
      int w = t >> 6;
      gr[w][0] = p0; gr[w][1] = p1; gr[w][2] = p2; gr[w][3] = p3;
    }
    __syncthreads();
    if (t == 0) {
      const int slot = b & 63;
      #pragma unroll
      for (int k = 0; k < 4; ++k) {
        float p = gr[0][k] + gr[1][k] + gr[2][k] + gr[3][k];
        atomicAdd(ws + WS_SCALPAD + (3 + k) * 64 + slot, p);
      }
    }
  }
}

// ---------------- Phase 4: write the 2071 updated rows ---------------------
__global__ __launch_bounds__(256, 4) void k_phase4(
    const float* __restrict__ ages, const float* __restrict__ ws,
    float* __restrict__ outn)
{
  const int b = blockIdx.x;
  const int t = threadIdx.x;

  // reduce the scalar pad (7 scalars x 64 slots) in wave 0
  __shared__ float s_scal[7];
  if (t < 64) {
    #pragma unroll
    for (int k = 0; k < 7; ++k) {
      float v = ws[WS_SCALPAD + k * 64 + t];
      #pragma unroll
      for (int m = 1; m < 64; m <<= 1) v += __shfl_xor(v, m);
      if (t == 0) s_scal[k] = v;
    }
  }
  __syncthreads();

  const float sii = s_scal[0];
  int row; float c, smm, smi; const float* mix;
  if (b < NXUPD) {
    row = b;
    float a = ages[row];
    float rsum = ws[WS_RESPP + row] + ws[WS_RESPP + 2048 + row] +
                 ws[WS_RESPP + 4096 + row] + ws[WS_RESPP + 6144 + row];
    c = (rsum / ws[WS_SCAL + 7]) / a;   // xvals[row] / age
    mix = ws + WS_MIXX; smm = s_scal[1]; smi = s_scal[2];
  } else {
    int k = b - NXUPD;
    row = ((const int*)(ws + WS_SELROW))[k];
    c = ws[WS_SELC + k];
    if (k < ZTOPK) { mix = ws + WS_MIXZ; smm = s_scal[3]; smi = s_scal[4]; }
    else           { mix = ws + WS_MIXY; smm = s_scal[5]; smi = s_scal[6]; }
  }
  // ||mix + c*inpt||^2 = smm + 2c*smi + c^2*sii
  const float inv = 1.f / (sqrtf(fmaf(c, fmaf(c, sii, 2.f * smi), smm)) + 1e-12f);
  const float* inpt = ws + WS_INPT;
  float* dst = outn + (size_t)row * DD;
  #pragma unroll
  for (int k = 0; k < 6; ++k) {
    const int i = t + 256 * k;
    v4f m4 = ((const v4f*)(mix))[i];
    v4f i4 = ((const v4f*)(inpt))[i];
    v4f o = (m4 + c * i4) * inv;
    __builtin_nontemporal_store(o, (v4f*)dst + i);
  }
  if (t < 16) {
    const int i = 1536 + t;
    v4f m4 = ((const v4f*)(mix))[i];
    v4f i4 = ((const v4f*)(inpt))[i];
    v4f o = (m4 + c * i4) * inv;
    __builtin_nontemporal_store(o, (v4f*)dst + i);
  }
}

// ---------------- launcher -------------------------------------------------
extern "C" void kernel_launch(void* const* d_in, const int* in_sizes, int n_in,
                              void* d_out, int out_size, void* d_ws, size_t ws_size,
                              hipStream_t stream)
{
  (void)in_sizes; (void)n_in; (void)out_size; (void)ws_size;
  const float* x    = (const float*)d_in[0];
  const float* zin  = (const float*)d_in[1];   // setup order: x, z, y_response, neurons, ages
  const float* yr   = (const float*)d_in[2];
  const float* neur = (const float*)d_in[3];
  const float* ages = (const float*)d_in[4];
  float* out = (float*)d_out;
  float* ws  = (float*)d_ws;

  k_phase1<<<XBLKS + YZBLKS + AUXBLKS, 256, 0, stream>>>(x, yr, zin, neur, ages, ws, out);
  k_phase2<<<1, 1024, 0, stream>>>(ages, ws, out);
  k_phase3<<<RBLKS + GBLKS, 256, 0, stream>>>(neur, out + OUT_NEUR, ws);
  k_phase4<<<NXUPD + ZTOPK + TOPK, 256, 0, stream>>>(ages, ws, out + OUT_NEUR);
}